// Round 4
// baseline (1097.852 us; speedup 1.0000x reference)
//
#include <hip/hip_runtime.h>
#include <math.h>

#define D 2048
#define S_LEN 4096
#define NB 4
#define NTOK (NB * S_LEN)  // 16384

__device__ __forceinline__ float gelu_tanh(float v) {
    const float c = 0.7978845608028654f;
    float t = tanhf(c * (v + 0.044715f * v * v * v));
    return 0.5f * v * (1.0f + t);
}

// ---------------- K0: one-time weight transposes for coalesced per-f loads
// W1 [D][16] -> W1t [16][D] ;  V [D][4] -> Vt [4][D]
__global__ __launch_bounds__(256) void k0_transpose(
        const float* __restrict__ W1, const float* __restrict__ V,
        float* __restrict__ W1t, float* __restrict__ Vt)
{
    const int id = blockIdx.x * 256 + threadIdx.x;
    if (id < D * 16) {
        const int d = id >> 4, f = id & 15;
        W1t[f * D + d] = W1[id];
    } else {
        const int id2 = id - D * 16;          // < D*4
        const int d = id2 >> 2, r = id2 & 3;
        Vt[r * D + d] = V[id2];
    }
}

// ---------------- K1: u[t][r] = rsqrt(mean(x^2)+eps) * sum_d x[d]*nw[d]*V[d][r]
// 2 tokens/wave, VGPR capped to 128 -> 4 waves/SIMD (was latency-bound at low occupancy)
__global__ __launch_bounds__(256, 4) void k1_u_kernel(
        const float* __restrict__ x, const float* __restrict__ nw,
        const float* __restrict__ Vt, float* __restrict__ u)
{
    const int gwave = (blockIdx.x * 256 + threadIdx.x) >> 6;
    const int lane  = threadIdx.x & 63;
    const int t0 = gwave * 2;                  // 2 tokens per wave

    float ss[2] = {0.f, 0.f};
    float uv[2][4] = {};

    #pragma unroll
    for (int j = 0; j < 8; ++j) {
        const int d0 = j * 256 + lane * 4;
        const float4 nw4 = *reinterpret_cast<const float4*>(nw + d0);
        float4 z4[2];
        #pragma unroll
        for (int tk = 0; tk < 2; ++tk) {
            const float4 xv = *reinterpret_cast<const float4*>(x + (size_t)(t0 + tk) * D + d0);
            ss[tk] += xv.x*xv.x + xv.y*xv.y + xv.z*xv.z + xv.w*xv.w;
            z4[tk].x = xv.x*nw4.x; z4[tk].y = xv.y*nw4.y;
            z4[tk].z = xv.z*nw4.z; z4[tk].w = xv.w*nw4.w;
        }
        #pragma unroll
        for (int r = 0; r < 4; ++r) {
            const float4 vv = *reinterpret_cast<const float4*>(Vt + r * D + d0);  // coalesced
            #pragma unroll
            for (int tk = 0; tk < 2; ++tk)
                uv[tk][r] += z4[tk].x*vv.x + z4[tk].y*vv.y + z4[tk].z*vv.z + z4[tk].w*vv.w;
        }
    }
    #pragma unroll
    for (int m = 1; m < 64; m <<= 1) {
        #pragma unroll
        for (int tk = 0; tk < 2; ++tk) {
            ss[tk] += __shfl_xor(ss[tk], m);
            #pragma unroll
            for (int r = 0; r < 4; ++r) uv[tk][r] += __shfl_xor(uv[tk][r], m);
        }
    }
    if (lane < 8) {
        float ssv = ss[0], uvv = uv[0][0];
        #pragma unroll
        for (int tk = 0; tk < 2; ++tk)
            #pragma unroll
            for (int r = 0; r < 4; ++r)
                if (lane == tk * 4 + r) { ssv = ss[tk]; uvv = uv[tk][r]; }
        const float rstd = rsqrtf(ssv * (1.0f / 2048.0f) + 1e-6f);
        u[(size_t)t0 * 4 + lane] = rstd * uvv;  // contiguous 32B store
    }
}

// ---------------- K2: chunked scan  h_t = a*h_{t-1} + u_t  per (b, r) series
__global__ __launch_bounds__(256) void k2_scan_kernel(
        const float* __restrict__ u, const float* __restrict__ a_logit,
        float* __restrict__ hs)
{
    __shared__ float lds[256];
    const int b = blockIdx.x >> 2;
    const int r = blockIdx.x & 3;
    const int i = threadIdx.x;
    const float a = 1.0f / (1.0f + expf(-a_logit[r]));
    const float* up = u  + (size_t)b * S_LEN * 4 + r;
    float*       hp = hs + (size_t)b * S_LEN * 4 + r;

    float ul[16];
    float h = 0.f;
    const int s0 = i * 16;
    #pragma unroll
    for (int k = 0; k < 16; ++k) { ul[k] = up[(size_t)(s0 + k) * 4]; h = a * h + ul[k]; }

    const float a2 = a*a, a4 = a2*a2, a8 = a4*a4;
    float m = a8 * a8;  // a^16
    float run = h;
    lds[i] = run;
    for (int off = 1; off < 256; off <<= 1) {
        __syncthreads();
        const float v = (i >= off) ? lds[i - off] : 0.f;
        __syncthreads();
        run += m * v;
        lds[i] = run;
        m *= m;
    }
    __syncthreads();
    float hh = (i == 0) ? 0.f : lds[i - 1];
    #pragma unroll
    for (int k = 0; k < 16; ++k) { hh = a * hh + ul[k]; hp[(size_t)(s0 + k) * 4] = hh; }
}

// ---------------- K3: fused  x2 = x + hs*U^T ; rms2 ; t = gelu(n2@W1) ; out = x2 + t@W2
// 2 tokens/wave (no scratch, verified round 3). VGPR capped to 170 (3 waves/SIMD):
// natural allocation was 224 (pure pipelining slack) -> 2 waves/SIMD, latency-bound.
// Accumulator set is only ~42 regs, so the cap trims pipelining, cannot force array spill.
__global__ __launch_bounds__(256, 3) void k3_fused_kernel(
        const float* __restrict__ x, const float* __restrict__ nw,
        const float* __restrict__ U, const float* __restrict__ hs,
        const float* __restrict__ W1t, const float* __restrict__ W2,
        float* __restrict__ out)
{
    __shared__ float reds[4][2][20];
    __shared__ float tvs[4][32];
    const int w = threadIdx.x >> 6;
    const int lane = threadIdx.x & 63;
    const int gwave = blockIdx.x * 4 + w;
    const int t0 = gwave * 2;                    // 2 tokens per wave
    const float4* U4  = reinterpret_cast<const float4*>(U);
    const float4* hs4 = reinterpret_cast<const float4*>(hs);
    float4 hv[2];
    #pragma unroll
    for (int tk = 0; tk < 2; ++tk) hv[tk] = hs4[t0 + tk];

    float ss[2] = {0.f, 0.f};
    float pf[2][16] = {};

    // phase A: ss (rms2) and pf (n2 @ W1) accumulation
    #pragma unroll
    for (int j = 0; j < 8; ++j) {
        const int d0 = j * 256 + lane * 4;
        const float4 nw4 = *reinterpret_cast<const float4*>(nw + d0);
        float4 z4[2];
        {
            float4 ur[4];
            #pragma unroll
            for (int i = 0; i < 4; ++i) ur[i] = U4[d0 + i];
            #pragma unroll
            for (int tk = 0; tk < 2; ++tk) {
                const float4 xv = *reinterpret_cast<const float4*>(x + (size_t)(t0 + tk) * D + d0);
                const float y0 = hv[tk].x*ur[0].x + hv[tk].y*ur[0].y + hv[tk].z*ur[0].z + hv[tk].w*ur[0].w;
                const float y1 = hv[tk].x*ur[1].x + hv[tk].y*ur[1].y + hv[tk].z*ur[1].z + hv[tk].w*ur[1].w;
                const float y2 = hv[tk].x*ur[2].x + hv[tk].y*ur[2].y + hv[tk].z*ur[2].z + hv[tk].w*ur[2].w;
                const float y3 = hv[tk].x*ur[3].x + hv[tk].y*ur[3].y + hv[tk].z*ur[3].z + hv[tk].w*ur[3].w;
                const float x20 = xv.x + y0, x21 = xv.y + y1, x22 = xv.z + y2, x23 = xv.w + y3;
                ss[tk] += x20*x20 + x21*x21 + x22*x22 + x23*x23;
                z4[tk].x = x20*nw4.x; z4[tk].y = x21*nw4.y;
                z4[tk].z = x22*nw4.z; z4[tk].w = x23*nw4.w;
            }
        }
        #pragma unroll
        for (int f = 0; f < 16; ++f) {
            const float4 wv = *reinterpret_cast<const float4*>(W1t + f * D + d0);  // coalesced
            #pragma unroll
            for (int tk = 0; tk < 2; ++tk)
                pf[tk][f] += z4[tk].x*wv.x + z4[tk].y*wv.y + z4[tk].z*wv.z + z4[tk].w*wv.w;
        }
    }

    // in-wave butterfly reduction over 34 values (all lanes end with full sums)
    #pragma unroll
    for (int m = 1; m < 64; m <<= 1) {
        #pragma unroll
        for (int tk = 0; tk < 2; ++tk) {
            ss[tk] += __shfl_xor(ss[tk], m);
            #pragma unroll
            for (int f = 0; f < 16; ++f) pf[tk][f] += __shfl_xor(pf[tk][f], m);
        }
    }
    if (lane == 0) {
        #pragma unroll
        for (int tk = 0; tk < 2; ++tk) {
            reds[w][tk][16] = ss[tk];
            #pragma unroll
            for (int f = 0; f < 16; ++f) reds[w][tk][f] = pf[tk][f];
        }
    }
    __syncthreads();
    if (lane < 32) {
        const int mytk = lane >> 4, myf = lane & 15;  // 32 lanes = 2 tokens x 16 f
        const float rstd = rsqrtf(reds[w][mytk][16] * (1.0f / 2048.0f) + 1e-6f);
        tvs[w][lane] = gelu_tanh(rstd * reds[w][mytk][myf]);
    }
    __syncthreads();
    float tvv[2][16];   // live only in phase C; pf[] is dead here
    #pragma unroll
    for (int tk = 0; tk < 2; ++tk)
        #pragma unroll
        for (int f = 0; f < 16; ++f) tvv[tk][f] = tvs[w][tk * 16 + f];

    // phase C: out = x2 + t @ W2  (x2 recomputed; x row is L2-hot from phase A)
    #pragma unroll
    for (int j = 0; j < 8; ++j) {
        const int d0 = j * 256 + lane * 4;
        float4 ur[4];
        #pragma unroll
        for (int i = 0; i < 4; ++i) ur[i] = U4[d0 + i];
        float4 acc[2];
        #pragma unroll
        for (int tk = 0; tk < 2; ++tk) {
            const float4 xv = *reinterpret_cast<const float4*>(x + (size_t)(t0 + tk) * D + d0);
            acc[tk].x = xv.x + hv[tk].x*ur[0].x + hv[tk].y*ur[0].y + hv[tk].z*ur[0].z + hv[tk].w*ur[0].w;
            acc[tk].y = xv.y + hv[tk].x*ur[1].x + hv[tk].y*ur[1].y + hv[tk].z*ur[1].z + hv[tk].w*ur[1].w;
            acc[tk].z = xv.z + hv[tk].x*ur[2].x + hv[tk].y*ur[2].y + hv[tk].z*ur[2].z + hv[tk].w*ur[2].w;
            acc[tk].w = xv.w + hv[tk].x*ur[3].x + hv[tk].y*ur[3].y + hv[tk].z*ur[3].z + hv[tk].w*ur[3].w;
        }
        #pragma unroll
        for (int f = 0; f < 16; ++f) {
            const float4 w2v = *reinterpret_cast<const float4*>(W2 + (size_t)f * D + d0);
            #pragma unroll
            for (int tk = 0; tk < 2; ++tk) {
                acc[tk].x += tvv[tk][f] * w2v.x;
                acc[tk].y += tvv[tk][f] * w2v.y;
                acc[tk].z += tvv[tk][f] * w2v.z;
                acc[tk].w += tvv[tk][f] * w2v.w;
            }
        }
        #pragma unroll
        for (int tk = 0; tk < 2; ++tk)
            *reinterpret_cast<float4*>(out + (size_t)(t0 + tk) * D + d0) = acc[tk];
    }
}

extern "C" void kernel_launch(void* const* d_in, const int* in_sizes, int n_in,
                              void* d_out, int out_size, void* d_ws, size_t ws_size,
                              hipStream_t stream)
{
    (void)in_sizes; (void)n_in; (void)out_size; (void)ws_size;
    const float* x  = (const float*)d_in[0];
    const float* nw = (const float*)d_in[1];
    const float* V  = (const float*)d_in[2];
    const float* U  = (const float*)d_in[3];
    const float* al = (const float*)d_in[4];
    const float* W1 = (const float*)d_in[5];
    const float* W2 = (const float*)d_in[6];
    float* out = (float*)d_out;
    float* u   = (float*)d_ws;                 // [NTOK][4]
    float* hs  = u + (size_t)NTOK * 4;         // [NTOK][4]
    float* W1t = hs + (size_t)NTOK * 4;        // [16][D]
    float* Vt  = W1t + (size_t)16 * D;         // [4][D]
    // total workspace: 172032 floats = 688 KB

    k0_transpose  <<<dim3(160),       dim3(256), 0, stream>>>(W1, V, W1t, Vt);
    k1_u_kernel   <<<dim3(NTOK / 8),  dim3(256), 0, stream>>>(x, nw, Vt, u);
    k2_scan_kernel<<<dim3(16),        dim3(256), 0, stream>>>(u, al, hs);
    k3_fused_kernel<<<dim3(NTOK / 8), dim3(256), 0, stream>>>(x, nw, U, hs, W1t, W2, out);
}

// Round 5
// 452.123 us; speedup vs baseline: 2.4282x; 2.4282x over previous
//
#include <hip/hip_runtime.h>
#include <math.h>

#define D 2048
#define S_LEN 4096
#define NB 4
#define NTOK (NB * S_LEN)  // 16384

__device__ __forceinline__ float gelu_tanh(float v) {
    const float c = 0.7978845608028654f;
    float t = tanhf(c * (v + 0.044715f * v * v * v));
    return 0.5f * v * (1.0f + t);
}

// ---------------- K0: one-time weight transposes for coalesced per-f loads
// W1 [D][16] -> W1t [16][D] ;  V [D][4] -> Vt [4][D]
__global__ __launch_bounds__(256) void k0_transpose(
        const float* __restrict__ W1, const float* __restrict__ V,
        float* __restrict__ W1t, float* __restrict__ Vt)
{
    const int id = blockIdx.x * 256 + threadIdx.x;
    if (id < D * 16) {
        const int d = id >> 4, f = id & 15;
        W1t[f * D + d] = W1[id];
    } else {
        const int id2 = id - D * 16;          // < D*4
        const int d = id2 >> 2, r = id2 & 3;
        Vt[r * D + d] = V[id2];
    }
}

// ---------------- K1: u[t][r] = rsqrt(mean(x^2)+eps) * sum_d x[d]*nw[d]*V[d][r]
// 2 tokens/wave (round-4 config, kept: improved rest-time ~30 us, no spill signature)
__global__ __launch_bounds__(256, 4) void k1_u_kernel(
        const float* __restrict__ x, const float* __restrict__ nw,
        const float* __restrict__ Vt, float* __restrict__ u)
{
    const int gwave = (blockIdx.x * 256 + threadIdx.x) >> 6;
    const int lane  = threadIdx.x & 63;
    const int t0 = gwave * 2;                  // 2 tokens per wave

    float ss[2] = {0.f, 0.f};
    float uv[2][4] = {};

    #pragma unroll
    for (int j = 0; j < 8; ++j) {
        const int d0 = j * 256 + lane * 4;
        const float4 nw4 = *reinterpret_cast<const float4*>(nw + d0);
        float4 z4[2];
        #pragma unroll
        for (int tk = 0; tk < 2; ++tk) {
            const float4 xv = *reinterpret_cast<const float4*>(x + (size_t)(t0 + tk) * D + d0);
            ss[tk] += xv.x*xv.x + xv.y*xv.y + xv.z*xv.z + xv.w*xv.w;
            z4[tk].x = xv.x*nw4.x; z4[tk].y = xv.y*nw4.y;
            z4[tk].z = xv.z*nw4.z; z4[tk].w = xv.w*nw4.w;
        }
        #pragma unroll
        for (int r = 0; r < 4; ++r) {
            const float4 vv = *reinterpret_cast<const float4*>(Vt + r * D + d0);  // coalesced
            #pragma unroll
            for (int tk = 0; tk < 2; ++tk)
                uv[tk][r] += z4[tk].x*vv.x + z4[tk].y*vv.y + z4[tk].z*vv.z + z4[tk].w*vv.w;
        }
    }
    #pragma unroll
    for (int m = 1; m < 64; m <<= 1) {
        #pragma unroll
        for (int tk = 0; tk < 2; ++tk) {
            ss[tk] += __shfl_xor(ss[tk], m);
            #pragma unroll
            for (int r = 0; r < 4; ++r) uv[tk][r] += __shfl_xor(uv[tk][r], m);
        }
    }
    if (lane < 8) {
        float ssv = ss[0], uvv = uv[0][0];
        #pragma unroll
        for (int tk = 0; tk < 2; ++tk)
            #pragma unroll
            for (int r = 0; r < 4; ++r)
                if (lane == tk * 4 + r) { ssv = ss[tk]; uvv = uv[tk][r]; }
        const float rstd = rsqrtf(ssv * (1.0f / 2048.0f) + 1e-6f);
        u[(size_t)t0 * 4 + lane] = rstd * uvv;  // contiguous 32B store
    }
}

// ---------------- K2: chunked scan  h_t = a*h_{t-1} + u_t  per (b, r) series
__global__ __launch_bounds__(256) void k2_scan_kernel(
        const float* __restrict__ u, const float* __restrict__ a_logit,
        float* __restrict__ hs)
{
    __shared__ float lds[256];
    const int b = blockIdx.x >> 2;
    const int r = blockIdx.x & 3;
    const int i = threadIdx.x;
    const float a = 1.0f / (1.0f + expf(-a_logit[r]));
    const float* up = u  + (size_t)b * S_LEN * 4 + r;
    float*       hp = hs + (size_t)b * S_LEN * 4 + r;

    float ul[16];
    float h = 0.f;
    const int s0 = i * 16;
    #pragma unroll
    for (int k = 0; k < 16; ++k) { ul[k] = up[(size_t)(s0 + k) * 4]; h = a * h + ul[k]; }

    const float a2 = a*a, a4 = a2*a2, a8 = a4*a4;
    float m = a8 * a8;  // a^16
    float run = h;
    lds[i] = run;
    for (int off = 1; off < 256; off <<= 1) {
        __syncthreads();
        const float v = (i >= off) ? lds[i - off] : 0.f;
        __syncthreads();
        run += m * v;
        lds[i] = run;
        m *= m;
    }
    __syncthreads();
    float hh = (i == 0) ? 0.f : lds[i - 1];
    #pragma unroll
    for (int k = 0; k < 16; ++k) { hh = a * hh + ul[k]; hp[(size_t)(s0 + k) * 4] = hh; }
}

// ---------------- K3a: x2 = x + hs*U^T ; rms2 ; tv = gelu(n2 @ W1)   (phase A only)
// NO __launch_bounds__ min-waves hint (confirmed twice: hints -> wholesale scratch spill).
// Phase C removed -> lower natural VGPR -> better occupancy than the fused 224-reg kernel.
__global__ __launch_bounds__(256) void k3a_kernel(
        const float* __restrict__ x, const float* __restrict__ nw,
        const float* __restrict__ U, const float* __restrict__ hs,
        const float* __restrict__ W1t, float* __restrict__ tv)
{
    __shared__ float reds[4][2][20];
    const int w = threadIdx.x >> 6;
    const int lane = threadIdx.x & 63;
    const int gwave = blockIdx.x * 4 + w;
    const int t0 = gwave * 2;                    // 2 tokens per wave
    const float4* U4  = reinterpret_cast<const float4*>(U);
    const float4* hs4 = reinterpret_cast<const float4*>(hs);
    float4 hv[2];
    #pragma unroll
    for (int tk = 0; tk < 2; ++tk) hv[tk] = hs4[t0 + tk];

    float ss[2] = {0.f, 0.f};
    float pf[2][16] = {};

    #pragma unroll
    for (int j = 0; j < 8; ++j) {
        const int d0 = j * 256 + lane * 4;
        const float4 nw4 = *reinterpret_cast<const float4*>(nw + d0);
        float4 z4[2];
        {
            float4 ur[4];
            #pragma unroll
            for (int i = 0; i < 4; ++i) ur[i] = U4[d0 + i];
            #pragma unroll
            for (int tk = 0; tk < 2; ++tk) {
                const float4 xv = *reinterpret_cast<const float4*>(x + (size_t)(t0 + tk) * D + d0);
                const float y0 = hv[tk].x*ur[0].x + hv[tk].y*ur[0].y + hv[tk].z*ur[0].z + hv[tk].w*ur[0].w;
                const float y1 = hv[tk].x*ur[1].x + hv[tk].y*ur[1].y + hv[tk].z*ur[1].z + hv[tk].w*ur[1].w;
                const float y2 = hv[tk].x*ur[2].x + hv[tk].y*ur[2].y + hv[tk].z*ur[2].z + hv[tk].w*ur[2].w;
                const float y3 = hv[tk].x*ur[3].x + hv[tk].y*ur[3].y + hv[tk].z*ur[3].z + hv[tk].w*ur[3].w;
                const float x20 = xv.x + y0, x21 = xv.y + y1, x22 = xv.z + y2, x23 = xv.w + y3;
                ss[tk] += x20*x20 + x21*x21 + x22*x22 + x23*x23;
                z4[tk].x = x20*nw4.x; z4[tk].y = x21*nw4.y;
                z4[tk].z = x22*nw4.z; z4[tk].w = x23*nw4.w;
            }
        }
        #pragma unroll
        for (int f = 0; f < 16; ++f) {
            const float4 wv = *reinterpret_cast<const float4*>(W1t + f * D + d0);  // coalesced
            #pragma unroll
            for (int tk = 0; tk < 2; ++tk)
                pf[tk][f] += z4[tk].x*wv.x + z4[tk].y*wv.y + z4[tk].z*wv.z + z4[tk].w*wv.w;
        }
    }

    // in-wave butterfly reduction over 34 values
    #pragma unroll
    for (int m = 1; m < 64; m <<= 1) {
        #pragma unroll
        for (int tk = 0; tk < 2; ++tk) {
            ss[tk] += __shfl_xor(ss[tk], m);
            #pragma unroll
            for (int f = 0; f < 16; ++f) pf[tk][f] += __shfl_xor(pf[tk][f], m);
        }
    }
    if (lane == 0) {
        #pragma unroll
        for (int tk = 0; tk < 2; ++tk) {
            reds[w][tk][16] = ss[tk];
            #pragma unroll
            for (int f = 0; f < 16; ++f) reds[w][tk][f] = pf[tk][f];
        }
    }
    __syncthreads();
    if (lane < 32) {
        const int mytk = lane >> 4, myf = lane & 15;  // lane = mytk*16+myf
        const float rstd = rsqrtf(reds[w][mytk][16] * (1.0f / 2048.0f) + 1e-6f);
        // (t0+mytk)*16+myf == t0*16+lane : contiguous 128B store per wave
        tv[(size_t)t0 * 16 + lane] = gelu_tanh(rstd * reds[w][mytk][myf]);
    }
}

// ---------------- K3b: out = (x + hs*U^T) + tv @ W2   (phase C only)
// Small live state (tvv 32 + hv 8 + acc 8) -> naturally low VGPR, high occupancy.
__global__ __launch_bounds__(256) void k3b_kernel(
        const float* __restrict__ x, const float* __restrict__ U,
        const float* __restrict__ hs, const float* __restrict__ tv,
        const float* __restrict__ W2, float* __restrict__ out)
{
    const int gwave = (blockIdx.x * 256 + threadIdx.x) >> 6;
    const int lane  = threadIdx.x & 63;
    const int t0 = gwave * 2;
    const float4* U4  = reinterpret_cast<const float4*>(U);
    const float4* hs4 = reinterpret_cast<const float4*>(hs);
    const float4* tv4 = reinterpret_cast<const float4*>(tv);
    float4 hv[2];
    #pragma unroll
    for (int tk = 0; tk < 2; ++tk) hv[tk] = hs4[t0 + tk];

    float tvv[2][16];
    #pragma unroll
    for (int tk = 0; tk < 2; ++tk)
        #pragma unroll
        for (int c = 0; c < 4; ++c) {
            const float4 t4 = tv4[(size_t)(t0 + tk) * 4 + c];   // broadcast, L2-hot
            tvv[tk][c*4+0] = t4.x; tvv[tk][c*4+1] = t4.y;
            tvv[tk][c*4+2] = t4.z; tvv[tk][c*4+3] = t4.w;
        }

    #pragma unroll
    for (int j = 0; j < 8; ++j) {
        const int d0 = j * 256 + lane * 4;
        float4 ur[4];
        #pragma unroll
        for (int i = 0; i < 4; ++i) ur[i] = U4[d0 + i];
        float4 acc[2];
        #pragma unroll
        for (int tk = 0; tk < 2; ++tk) {
            const float4 xv = *reinterpret_cast<const float4*>(x + (size_t)(t0 + tk) * D + d0);
            acc[tk].x = xv.x + hv[tk].x*ur[0].x + hv[tk].y*ur[0].y + hv[tk].z*ur[0].z + hv[tk].w*ur[0].w;
            acc[tk].y = xv.y + hv[tk].x*ur[1].x + hv[tk].y*ur[1].y + hv[tk].z*ur[1].z + hv[tk].w*ur[1].w;
            acc[tk].z = xv.z + hv[tk].x*ur[2].x + hv[tk].y*ur[2].y + hv[tk].z*ur[2].z + hv[tk].w*ur[2].w;
            acc[tk].w = xv.w + hv[tk].x*ur[3].x + hv[tk].y*ur[3].y + hv[tk].z*ur[3].z + hv[tk].w*ur[3].w;
        }
        #pragma unroll
        for (int f = 0; f < 16; ++f) {
            const float4 w2v = *reinterpret_cast<const float4*>(W2 + (size_t)f * D + d0);
            #pragma unroll
            for (int tk = 0; tk < 2; ++tk) {
                acc[tk].x += tvv[tk][f] * w2v.x;
                acc[tk].y += tvv[tk][f] * w2v.y;
                acc[tk].z += tvv[tk][f] * w2v.z;
                acc[tk].w += tvv[tk][f] * w2v.w;
            }
        }
        #pragma unroll
        for (int tk = 0; tk < 2; ++tk)
            *reinterpret_cast<float4*>(out + (size_t)(t0 + tk) * D + d0) = acc[tk];
    }
}

extern "C" void kernel_launch(void* const* d_in, const int* in_sizes, int n_in,
                              void* d_out, int out_size, void* d_ws, size_t ws_size,
                              hipStream_t stream)
{
    (void)in_sizes; (void)n_in; (void)out_size; (void)ws_size;
    const float* x  = (const float*)d_in[0];
    const float* nw = (const float*)d_in[1];
    const float* V  = (const float*)d_in[2];
    const float* U  = (const float*)d_in[3];
    const float* al = (const float*)d_in[4];
    const float* W1 = (const float*)d_in[5];
    const float* W2 = (const float*)d_in[6];
    float* out = (float*)d_out;
    float* u   = (float*)d_ws;                 // [NTOK][4]
    float* hs  = u + (size_t)NTOK * 4;         // [NTOK][4]
    float* W1t = hs + (size_t)NTOK * 4;        // [16][D]
    float* Vt  = W1t + (size_t)16 * D;         // [4][D]
    float* tv  = Vt + (size_t)4 * D;           // [NTOK][16]
    // total workspace: 434176 floats ~= 1.7 MB

    k0_transpose  <<<dim3(160),       dim3(256), 0, stream>>>(W1, V, W1t, Vt);
    k1_u_kernel   <<<dim3(NTOK / 8),  dim3(256), 0, stream>>>(x, nw, Vt, u);
    k2_scan_kernel<<<dim3(16),        dim3(256), 0, stream>>>(u, al, hs);
    k3a_kernel    <<<dim3(NTOK / 8),  dim3(256), 0, stream>>>(x, nw, U, hs, W1t, tv);
    k3b_kernel    <<<dim3(NTOK / 8),  dim3(256), 0, stream>>>(x, U, hs, tv, W2, out);
}

// Round 6
// 338.957 us; speedup vs baseline: 3.2389x; 1.3339x over previous
//
#include <hip/hip_runtime.h>
#include <math.h>
#include <stdint.h>

#define D 2048
#define S_LEN 4096
#define NB 4
#define NTOK (NB * S_LEN)  // 16384

__device__ __forceinline__ float gelu_tanh(float v) {
    const float c = 0.7978845608028654f;
    float t = tanhf(c * (v + 0.044715f * v * v * v));
    return 0.5f * v * (1.0f + t);
}

// async global->LDS, 16B per lane (HW: lds dst = wave-uniform base + lane*16; global src per-lane)
// CK-style address-space casts: AS1 for global, AS3 via uintptr truncation (low 32b = LDS offset).
__device__ __forceinline__ void gload_lds16(const float* g, float* l) {
    __builtin_amdgcn_global_load_lds(
        (const __attribute__((address_space(1))) void*)g,
        (__attribute__((address_space(3))) void*)(uintptr_t)(uint32_t)(uintptr_t)l,
        16, 0, 0);
}

// ---------------- K0: one-time weight transposes
// W1 [D][16] -> W1t [16][D] ;  V [D][4] -> Vt [4][D] ;  U [D][4] -> Ut [4][D]
__global__ __launch_bounds__(256) void k0_transpose(
        const float* __restrict__ W1, const float* __restrict__ V, const float* __restrict__ U,
        float* __restrict__ W1t, float* __restrict__ Vt, float* __restrict__ Ut)
{
    const int id = blockIdx.x * 256 + threadIdx.x;
    if (id < D * 16) {
        const int d = id >> 4, f = id & 15;
        W1t[f * D + d] = W1[id];
    } else if (id < D * 16 + D * 4) {
        const int i2 = id - D * 16;
        Vt[(i2 & 3) * D + (i2 >> 2)] = V[i2];
    } else {
        const int i2 = id - D * 16 - D * 4;   // < D*4
        Ut[(i2 & 3) * D + (i2 >> 2)] = U[i2];
    }
}

// ---------------- K1: u[t][r] = rsqrt(mean(x^2)+eps) * sum_d x[d]*nw[d]*V[d][r]
// (unchanged from round 4/5 — best-known config)
__global__ __launch_bounds__(256, 4) void k1_u_kernel(
        const float* __restrict__ x, const float* __restrict__ nw,
        const float* __restrict__ Vt, float* __restrict__ u)
{
    const int gwave = (blockIdx.x * 256 + threadIdx.x) >> 6;
    const int lane  = threadIdx.x & 63;
    const int t0 = gwave * 2;

    float ss[2] = {0.f, 0.f};
    float uv[2][4] = {};

    #pragma unroll
    for (int j = 0; j < 8; ++j) {
        const int d0 = j * 256 + lane * 4;
        const float4 nw4 = *reinterpret_cast<const float4*>(nw + d0);
        float4 z4[2];
        #pragma unroll
        for (int tk = 0; tk < 2; ++tk) {
            const float4 xv = *reinterpret_cast<const float4*>(x + (size_t)(t0 + tk) * D + d0);
            ss[tk] += xv.x*xv.x + xv.y*xv.y + xv.z*xv.z + xv.w*xv.w;
            z4[tk].x = xv.x*nw4.x; z4[tk].y = xv.y*nw4.y;
            z4[tk].z = xv.z*nw4.z; z4[tk].w = xv.w*nw4.w;
        }
        #pragma unroll
        for (int r = 0; r < 4; ++r) {
            const float4 vv = *reinterpret_cast<const float4*>(Vt + r * D + d0);
            #pragma unroll
            for (int tk = 0; tk < 2; ++tk)
                uv[tk][r] += z4[tk].x*vv.x + z4[tk].y*vv.y + z4[tk].z*vv.z + z4[tk].w*vv.w;
        }
    }
    #pragma unroll
    for (int m = 1; m < 64; m <<= 1) {
        #pragma unroll
        for (int tk = 0; tk < 2; ++tk) {
            ss[tk] += __shfl_xor(ss[tk], m);
            #pragma unroll
            for (int r = 0; r < 4; ++r) uv[tk][r] += __shfl_xor(uv[tk][r], m);
        }
    }
    if (lane < 8) {
        float ssv = ss[0], uvv = uv[0][0];
        #pragma unroll
        for (int tk = 0; tk < 2; ++tk)
            #pragma unroll
            for (int r = 0; r < 4; ++r)
                if (lane == tk * 4 + r) { ssv = ss[tk]; uvv = uv[tk][r]; }
        const float rstd = rsqrtf(ssv * (1.0f / 2048.0f) + 1e-6f);
        u[(size_t)t0 * 4 + lane] = rstd * uvv;
    }
}

// ---------------- K2: chunked scan (unchanged)
__global__ __launch_bounds__(256) void k2_scan_kernel(
        const float* __restrict__ u, const float* __restrict__ a_logit,
        float* __restrict__ hs)
{
    __shared__ float lds[256];
    const int b = blockIdx.x >> 2;
    const int r = blockIdx.x & 3;
    const int i = threadIdx.x;
    const float a = 1.0f / (1.0f + expf(-a_logit[r]));
    const float* up = u  + (size_t)b * S_LEN * 4 + r;
    float*       hp = hs + (size_t)b * S_LEN * 4 + r;

    float ul[16];
    float h = 0.f;
    const int s0 = i * 16;
    #pragma unroll
    for (int k = 0; k < 16; ++k) { ul[k] = up[(size_t)(s0 + k) * 4]; h = a * h + ul[k]; }

    const float a2 = a*a, a4 = a2*a2, a8 = a4*a4;
    float m = a8 * a8;
    float run = h;
    lds[i] = run;
    for (int off = 1; off < 256; off <<= 1) {
        __syncthreads();
        const float v = (i >= off) ? lds[i - off] : 0.f;
        __syncthreads();
        run += m * v;
        lds[i] = run;
        m *= m;
    }
    __syncthreads();
    float hh = (i == 0) ? 0.f : lds[i - 1];
    #pragma unroll
    for (int k = 0; k < 16; ++k) { hh = a * hh + ul[k]; hp[(size_t)(s0 + k) * 4] = hh; }
}

// ---------------- K3: fused, block-cooperative LDS weight staging (double-buffered)
// Phase A slice layout in buf (floats): [0,256)=nw  [256,1280)=Ut(4x256)  [1280,5376)=W1t(16x256)
// Phase C slice layout: [0,4096)=W2(16x256)
// x2 = x + hs*Ut is written to `out` in phase A and re-read (L2-hot) in phase C.
#define SLICE_F 5376
__global__ __launch_bounds__(256) void k3_fused_kernel(
        const float* __restrict__ x, const float* __restrict__ nw,
        const float* __restrict__ Ut, const float* __restrict__ hs,
        const float* __restrict__ W1t, const float* __restrict__ W2,
        float* __restrict__ out)
{
    __shared__ float buf[2][SLICE_F];
    __shared__ float reds[4][2][20];
    __shared__ float tvs[4][32];
    const int w = threadIdx.x >> 6;
    const int lane = threadIdx.x & 63;
    const int t0 = (blockIdx.x * 4 + w) * 2;          // 2 tokens per wave, 8 per block
    const float4* hs4 = reinterpret_cast<const float4*>(hs);
    float4 hv[2];
    #pragma unroll
    for (int tk = 0; tk < 2; ++tk) hv[tk] = hs4[t0 + tk];

    float ss[2] = {0.f, 0.f};
    float pf[2][16] = {};

    // ---- phase A prologue: stage slice 0 (21 segments of 256 floats, split across waves)
    for (int s = w; s < 21; s += 4) {
        const float* src = (s == 0) ? (nw)
                         : (s < 5)  ? (Ut + (size_t)(s - 1) * D)
                                    : (W1t + (size_t)(s - 5) * D);
        gload_lds16(src + lane * 4, &buf[0][s * 256 + lane * 4]);
    }
    __syncthreads();   // implicit vmcnt(0) drain -> slice 0 visible

    for (int j = 0; j < 8; ++j) {
        const int cur = j & 1;
        if (j < 7) {   // issue next slice into the other buffer (completes at the barrier below)
            const int jn = (j + 1) * 256;
            for (int s = w; s < 21; s += 4) {
                const float* src = (s == 0) ? (nw + jn)
                                 : (s < 5)  ? (Ut + (size_t)(s - 1) * D + jn)
                                            : (W1t + (size_t)(s - 5) * D + jn);
                gload_lds16(src + lane * 4, &buf[cur ^ 1][s * 256 + lane * 4]);
            }
        }
        const float* bw = buf[cur];
        const int d0 = j * 256 + lane * 4;
        const float4 nw4 = *reinterpret_cast<const float4*>(bw + lane * 4);
        float4 ut[4];
        #pragma unroll
        for (int r = 0; r < 4; ++r)
            ut[r] = *reinterpret_cast<const float4*>(bw + 256 + r * 256 + lane * 4);
        float4 z4[2];
        #pragma unroll
        for (int tk = 0; tk < 2; ++tk) {
            const float4 xv = *reinterpret_cast<const float4*>(x + (size_t)(t0 + tk) * D + d0);
            const float x20 = xv.x + hv[tk].x*ut[0].x + hv[tk].y*ut[1].x + hv[tk].z*ut[2].x + hv[tk].w*ut[3].x;
            const float x21 = xv.y + hv[tk].x*ut[0].y + hv[tk].y*ut[1].y + hv[tk].z*ut[2].y + hv[tk].w*ut[3].y;
            const float x22 = xv.z + hv[tk].x*ut[0].z + hv[tk].y*ut[1].z + hv[tk].z*ut[2].z + hv[tk].w*ut[3].z;
            const float x23 = xv.w + hv[tk].x*ut[0].w + hv[tk].y*ut[1].w + hv[tk].z*ut[2].w + hv[tk].w*ut[3].w;
            ss[tk] += x20*x20 + x21*x21 + x22*x22 + x23*x23;
            float4 x2v; x2v.x = x20; x2v.y = x21; x2v.z = x22; x2v.w = x23;
            *reinterpret_cast<float4*>(out + (size_t)(t0 + tk) * D + d0) = x2v;   // x2 -> out
            z4[tk].x = x20*nw4.x; z4[tk].y = x21*nw4.y;
            z4[tk].z = x22*nw4.z; z4[tk].w = x23*nw4.w;
        }
        #pragma unroll
        for (int f = 0; f < 16; ++f) {
            const float4 wv = *reinterpret_cast<const float4*>(bw + 1280 + f * 256 + lane * 4);
            #pragma unroll
            for (int tk = 0; tk < 2; ++tk)
                pf[tk][f] += z4[tk].x*wv.x + z4[tk].y*wv.y + z4[tk].z*wv.z + z4[tk].w*wv.w;
        }
        __syncthreads();   // drains own staging vmcnt; protects both buffers
    }

    // ---- butterfly reduction over 34 values (round-3 verified structure)
    #pragma unroll
    for (int m = 1; m < 64; m <<= 1) {
        #pragma unroll
        for (int tk = 0; tk < 2; ++tk) {
            ss[tk] += __shfl_xor(ss[tk], m);
            #pragma unroll
            for (int f = 0; f < 16; ++f) pf[tk][f] += __shfl_xor(pf[tk][f], m);
        }
    }
    if (lane == 0) {
        #pragma unroll
        for (int tk = 0; tk < 2; ++tk) {
            reds[w][tk][16] = ss[tk];
            #pragma unroll
            for (int f = 0; f < 16; ++f) reds[w][tk][f] = pf[tk][f];
        }
    }
    __syncthreads();
    if (lane < 32) {
        const int mytk = lane >> 4, myf = lane & 15;
        const float rstd = rsqrtf(reds[w][mytk][16] * (1.0f / 2048.0f) + 1e-6f);
        tvs[w][lane] = gelu_tanh(rstd * reds[w][mytk][myf]);
    }
    __syncthreads();
    float tvv[2][16];   // pf dead here
    #pragma unroll
    for (int tk = 0; tk < 2; ++tk)
        #pragma unroll
        for (int f = 0; f < 16; ++f) tvv[tk][f] = tvs[w][tk * 16 + f];

    // ---- phase C prologue: stage W2 slice 0 (16 segments)
    for (int s = w; s < 16; s += 4)
        gload_lds16(W2 + (size_t)s * D + lane * 4, &buf[0][s * 256 + lane * 4]);
    __syncthreads();

    for (int j = 0; j < 8; ++j) {
        const int cur = j & 1;
        if (j < 7) {
            const int jn = (j + 1) * 256;
            for (int s = w; s < 16; s += 4)
                gload_lds16(W2 + (size_t)s * D + jn + lane * 4, &buf[cur ^ 1][s * 256 + lane * 4]);
        }
        const float* bw = buf[cur];
        const int d0 = j * 256 + lane * 4;
        float4 acc[2];
        #pragma unroll
        for (int tk = 0; tk < 2; ++tk)
            acc[tk] = *reinterpret_cast<const float4*>(out + (size_t)(t0 + tk) * D + d0);  // x2, L2-hot
        #pragma unroll
        for (int f = 0; f < 16; ++f) {
            const float4 w2v = *reinterpret_cast<const float4*>(bw + f * 256 + lane * 4);
            #pragma unroll
            for (int tk = 0; tk < 2; ++tk) {
                acc[tk].x += tvv[tk][f] * w2v.x;
                acc[tk].y += tvv[tk][f] * w2v.y;
                acc[tk].z += tvv[tk][f] * w2v.z;
                acc[tk].w += tvv[tk][f] * w2v.w;
            }
        }
        #pragma unroll
        for (int tk = 0; tk < 2; ++tk)
            *reinterpret_cast<float4*>(out + (size_t)(t0 + tk) * D + d0) = acc[tk];
        __syncthreads();
    }
}

extern "C" void kernel_launch(void* const* d_in, const int* in_sizes, int n_in,
                              void* d_out, int out_size, void* d_ws, size_t ws_size,
                              hipStream_t stream)
{
    (void)in_sizes; (void)n_in; (void)out_size; (void)ws_size;
    const float* x  = (const float*)d_in[0];
    const float* nw = (const float*)d_in[1];
    const float* V  = (const float*)d_in[2];
    const float* U  = (const float*)d_in[3];
    const float* al = (const float*)d_in[4];
    const float* W1 = (const float*)d_in[5];
    const float* W2 = (const float*)d_in[6];
    float* out = (float*)d_out;
    float* u   = (float*)d_ws;                 // [NTOK][4]
    float* hs  = u + (size_t)NTOK * 4;         // [NTOK][4]
    float* W1t = hs + (size_t)NTOK * 4;        // [16][D]
    float* Vt  = W1t + (size_t)16 * D;         // [4][D]
    float* Ut  = Vt + (size_t)4 * D;           // [4][D]
    // total workspace: 180224 floats = 704 KB

    k0_transpose  <<<dim3(192),       dim3(256), 0, stream>>>(W1, V, U, W1t, Vt, Ut);
    k1_u_kernel   <<<dim3(NTOK / 8),  dim3(256), 0, stream>>>(x, nw, Vt, u);
    k2_scan_kernel<<<dim3(16),        dim3(256), 0, stream>>>(u, al, hs);
    k3_fused_kernel<<<dim3(NTOK / 8), dim3(256), 0, stream>>>(x, nw, Ut, hs, W1t, W2, out);
}

// Round 8
// 320.698 us; speedup vs baseline: 3.4233x; 1.0569x over previous
//
#include <hip/hip_runtime.h>
#include <math.h>
#include <stdint.h>

#define D 2048
#define S_LEN 4096
#define NB 4
#define NTOK (NB * S_LEN)  // 16384

__device__ __forceinline__ float gelu_tanh(float v) {
    const float c = 0.7978845608028654f;
    float t = tanhf(c * (v + 0.044715f * v * v * v));
    return 0.5f * v * (1.0f + t);
}

// async global->LDS, 16B per lane (lds dst = wave-uniform base + lane*16; global src per-lane)
__device__ __forceinline__ void gload_lds16(const float* g, float* l) {
    __builtin_amdgcn_global_load_lds(
        (const __attribute__((address_space(1))) void*)g,
        (__attribute__((address_space(3))) void*)(uintptr_t)(uint32_t)(uintptr_t)l,
        16, 0, 0);
}

// ---------------- K0: one-time weight transposes
__global__ __launch_bounds__(256) void k0_transpose(
        const float* __restrict__ W1, const float* __restrict__ V, const float* __restrict__ U,
        float* __restrict__ W1t, float* __restrict__ Vt, float* __restrict__ Ut)
{
    const int id = blockIdx.x * 256 + threadIdx.x;
    if (id < D * 16) {
        const int d = id >> 4, f = id & 15;
        W1t[f * D + d] = W1[id];
    } else if (id < D * 16 + D * 4) {
        const int i2 = id - D * 16;
        Vt[(i2 & 3) * D + (i2 >> 2)] = V[i2];
    } else {
        const int i2 = id - D * 16 - D * 4;   // < D*4
        Ut[(i2 & 3) * D + (i2 >> 2)] = U[i2];
    }
}

// ---------------- K1: u[t][r] = rsqrt(mean(x^2)+eps) * sum_d x[d]*nw[d]*V[d][r]
// one-shot LDS staging of nw (2048 f) + Vt (4x2048 f) = 40 KB; weights loop-invariant,
// so no double-buffer / no in-loop barriers. x streamed from global.
__global__ __launch_bounds__(256) void k1_u_kernel(
        const float* __restrict__ x, const float* __restrict__ nw,
        const float* __restrict__ Vt, float* __restrict__ u)
{
    __shared__ float lw[10240];   // [0,2048)=nw  [2048,10240)=Vt rows
    const int w = threadIdx.x >> 6;
    const int lane  = threadIdx.x & 63;
    const int t0 = ((blockIdx.x * 256 + threadIdx.x) >> 6) * 2;

    // stage: 40 segments of 256 floats, split across the 4 waves
    for (int s = w; s < 40; s += 4) {
        const int base = s * 256;
        const float* src = (base < 2048) ? (nw + base) : (Vt + base - 2048);
        gload_lds16(src + lane * 4, &lw[base + lane * 4]);
    }
    __syncthreads();   // vmcnt drain -> weights visible

    float ss[2] = {0.f, 0.f};
    float uv[2][4] = {};

    #pragma unroll
    for (int j = 0; j < 8; ++j) {
        const int d0 = j * 256 + lane * 4;
        const float4 nw4 = *reinterpret_cast<const float4*>(lw + d0);
        float4 z4[2];
        #pragma unroll
        for (int tk = 0; tk < 2; ++tk) {
            const float4 xv = *reinterpret_cast<const float4*>(x + (size_t)(t0 + tk) * D + d0);
            ss[tk] += xv.x*xv.x + xv.y*xv.y + xv.z*xv.z + xv.w*xv.w;
            z4[tk].x = xv.x*nw4.x; z4[tk].y = xv.y*nw4.y;
            z4[tk].z = xv.z*nw4.z; z4[tk].w = xv.w*nw4.w;
        }
        #pragma unroll
        for (int r = 0; r < 4; ++r) {
            const float4 vv = *reinterpret_cast<const float4*>(lw + 2048 + r * 2048 + d0);
            #pragma unroll
            for (int tk = 0; tk < 2; ++tk)
                uv[tk][r] += z4[tk].x*vv.x + z4[tk].y*vv.y + z4[tk].z*vv.z + z4[tk].w*vv.w;
        }
    }
    #pragma unroll
    for (int m = 1; m < 64; m <<= 1) {
        #pragma unroll
        for (int tk = 0; tk < 2; ++tk) {
            ss[tk] += __shfl_xor(ss[tk], m);
            #pragma unroll
            for (int r = 0; r < 4; ++r) uv[tk][r] += __shfl_xor(uv[tk][r], m);
        }
    }
    if (lane < 8) {
        float ssv = ss[0], uvv = uv[0][0];
        #pragma unroll
        for (int tk = 0; tk < 2; ++tk)
            #pragma unroll
            for (int r = 0; r < 4; ++r)
                if (lane == tk * 4 + r) { ssv = ss[tk]; uvv = uv[tk][r]; }
        const float rstd = rsqrtf(ssv * (1.0f / 2048.0f) + 1e-6f);
        u[(size_t)t0 * 4 + lane] = rstd * uvv;
    }
}

// ---------------- K2: scan over S, vectorized across the 4 ranks (u[t][.] is a float4)
// 4 blocks (one per batch) x 1024 threads, 4 tokens/thread, coalesced float4 loads/stores.
__global__ __launch_bounds__(1024) void k2_scan_kernel(
        const float* __restrict__ u, const float* __restrict__ a_logit,
        float* __restrict__ hs)
{
    __shared__ float4 lds[1024];
    const int b = blockIdx.x;
    const int i = threadIdx.x;
    const float4 al4 = *reinterpret_cast<const float4*>(a_logit);
    float4 a;
    a.x = 1.0f / (1.0f + expf(-al4.x));
    a.y = 1.0f / (1.0f + expf(-al4.y));
    a.z = 1.0f / (1.0f + expf(-al4.z));
    a.w = 1.0f / (1.0f + expf(-al4.w));
    const float4* up = reinterpret_cast<const float4*>(u) + (size_t)b * S_LEN;
    float4*       hp = reinterpret_cast<float4*>(hs)      + (size_t)b * S_LEN;

    const int s0 = i * 4;
    float4 ul[4];
    float4 h; h.x = 0.f; h.y = 0.f; h.z = 0.f; h.w = 0.f;
    #pragma unroll
    for (int k = 0; k < 4; ++k) {
        ul[k] = up[s0 + k];
        h.x = a.x * h.x + ul[k].x; h.y = a.y * h.y + ul[k].y;
        h.z = a.z * h.z + ul[k].z; h.w = a.w * h.w + ul[k].w;
    }

    float4 m;   // a^4 per component
    m.x = a.x*a.x; m.y = a.y*a.y; m.z = a.z*a.z; m.w = a.w*a.w;
    m.x *= m.x; m.y *= m.y; m.z *= m.z; m.w *= m.w;
    float4 run = h;
    lds[i] = run;
    for (int off = 1; off < 1024; off <<= 1) {
        __syncthreads();
        float4 v;
        if (i >= off) v = lds[i - off];
        else { v.x = 0.f; v.y = 0.f; v.z = 0.f; v.w = 0.f; }
        __syncthreads();
        run.x += m.x * v.x; run.y += m.y * v.y;
        run.z += m.z * v.z; run.w += m.w * v.w;
        lds[i] = run;
        m.x *= m.x; m.y *= m.y; m.z *= m.z; m.w *= m.w;
    }
    __syncthreads();
    float4 hh;
    if (i == 0) { hh.x = 0.f; hh.y = 0.f; hh.z = 0.f; hh.w = 0.f; }
    else hh = lds[i - 1];
    #pragma unroll
    for (int k = 0; k < 4; ++k) {
        hh.x = a.x * hh.x + ul[k].x; hh.y = a.y * hh.y + ul[k].y;
        hh.z = a.z * hh.z + ul[k].z; hh.w = a.w * hh.w + ul[k].w;
        hp[s0 + k] = hh;
    }
}

// ---------------- K3: fused, block-cooperative LDS weight staging (double-buffered)
// Phase A slice: [0,256)=nw [256,1280)=Ut(4x256) [1280,5376)=W1t(16x256)
// Phase C slice: [0,1024)=Ut(4x256) [1024,5120)=W2(16x256)
// x2 is RECOMPUTED in phase C (x L3-hot, Ut in LDS) -> out written exactly once (-128 MB HBM).
#define SLICE_F 5376
__global__ __launch_bounds__(256) void k3_fused_kernel(
        const float* __restrict__ x, const float* __restrict__ nw,
        const float* __restrict__ Ut, const float* __restrict__ hs,
        const float* __restrict__ W1t, const float* __restrict__ W2,
        float* __restrict__ out)
{
    __shared__ float buf[2][SLICE_F];
    __shared__ float reds[4][2][20];
    __shared__ float tvs[4][32];
    const int w = threadIdx.x >> 6;
    const int lane = threadIdx.x & 63;
    const int t0 = (blockIdx.x * 4 + w) * 2;          // 2 tokens per wave, 8 per block
    const float4* hs4 = reinterpret_cast<const float4*>(hs);
    float4 hv[2];
    #pragma unroll
    for (int tk = 0; tk < 2; ++tk) hv[tk] = hs4[t0 + tk];

    float ss[2] = {0.f, 0.f};
    float pf[2][16] = {};

    // ---- phase A prologue: stage slice 0 (21 segments)
    for (int s = w; s < 21; s += 4) {
        const float* src = (s == 0) ? (nw)
                         : (s < 5)  ? (Ut + (size_t)(s - 1) * D)
                                    : (W1t + (size_t)(s - 5) * D);
        gload_lds16(src + lane * 4, &buf[0][s * 256 + lane * 4]);
    }
    __syncthreads();

    for (int j = 0; j < 8; ++j) {
        const int cur = j & 1;
        if (j < 7) {
            const int jn = (j + 1) * 256;
            for (int s = w; s < 21; s += 4) {
                const float* src = (s == 0) ? (nw + jn)
                                 : (s < 5)  ? (Ut + (size_t)(s - 1) * D + jn)
                                            : (W1t + (size_t)(s - 5) * D + jn);
                gload_lds16(src + lane * 4, &buf[cur ^ 1][s * 256 + lane * 4]);
            }
        }
        const float* bw = buf[cur];
        const int d0 = j * 256 + lane * 4;
        const float4 nw4 = *reinterpret_cast<const float4*>(bw + lane * 4);
        float4 ut[4];
        #pragma unroll
        for (int r = 0; r < 4; ++r)
            ut[r] = *reinterpret_cast<const float4*>(bw + 256 + r * 256 + lane * 4);
        float4 z4[2];
        #pragma unroll
        for (int tk = 0; tk < 2; ++tk) {
            const float4 xv = *reinterpret_cast<const float4*>(x + (size_t)(t0 + tk) * D + d0);
            const float x20 = xv.x + hv[tk].x*ut[0].x + hv[tk].y*ut[1].x + hv[tk].z*ut[2].x + hv[tk].w*ut[3].x;
            const float x21 = xv.y + hv[tk].x*ut[0].y + hv[tk].y*ut[1].y + hv[tk].z*ut[2].y + hv[tk].w*ut[3].y;
            const float x22 = xv.z + hv[tk].x*ut[0].z + hv[tk].y*ut[1].z + hv[tk].z*ut[2].z + hv[tk].w*ut[3].z;
            const float x23 = xv.w + hv[tk].x*ut[0].w + hv[tk].y*ut[1].w + hv[tk].z*ut[2].w + hv[tk].w*ut[3].w;
            ss[tk] += x20*x20 + x21*x21 + x22*x22 + x23*x23;
            z4[tk].x = x20*nw4.x; z4[tk].y = x21*nw4.y;
            z4[tk].z = x22*nw4.z; z4[tk].w = x23*nw4.w;
        }
        #pragma unroll
        for (int f = 0; f < 16; ++f) {
            const float4 wv = *reinterpret_cast<const float4*>(bw + 1280 + f * 256 + lane * 4);
            #pragma unroll
            for (int tk = 0; tk < 2; ++tk)
                pf[tk][f] += z4[tk].x*wv.x + z4[tk].y*wv.y + z4[tk].z*wv.z + z4[tk].w*wv.w;
        }
        __syncthreads();
    }

    // ---- butterfly reduction over 34 values
    #pragma unroll
    for (int m = 1; m < 64; m <<= 1) {
        #pragma unroll
        for (int tk = 0; tk < 2; ++tk) {
            ss[tk] += __shfl_xor(ss[tk], m);
            #pragma unroll
            for (int f = 0; f < 16; ++f) pf[tk][f] += __shfl_xor(pf[tk][f], m);
        }
    }
    if (lane == 0) {
        #pragma unroll
        for (int tk = 0; tk < 2; ++tk) {
            reds[w][tk][16] = ss[tk];
            #pragma unroll
            for (int f = 0; f < 16; ++f) reds[w][tk][f] = pf[tk][f];
        }
    }
    __syncthreads();
    if (lane < 32) {
        const int mytk = lane >> 4, myf = lane & 15;
        const float rstd = rsqrtf(reds[w][mytk][16] * (1.0f / 2048.0f) + 1e-6f);
        tvs[w][lane] = gelu_tanh(rstd * reds[w][mytk][myf]);
    }
    __syncthreads();
    float tvv[2][16];
    #pragma unroll
    for (int tk = 0; tk < 2; ++tk)
        #pragma unroll
        for (int f = 0; f < 16; ++f) tvv[tk][f] = tvs[w][tk * 16 + f];

    // ---- phase C prologue: stage Ut+W2 slice 0 (20 segments)
    for (int s = w; s < 20; s += 4) {
        const float* src = (s < 4) ? (Ut + (size_t)s * D)
                                   : (W2 + (size_t)(s - 4) * D);
        gload_lds16(src + lane * 4, &buf[0][s * 256 + lane * 4]);
    }
    __syncthreads();

    for (int j = 0; j < 8; ++j) {
        const int cur = j & 1;
        if (j < 7) {
            const int jn = (j + 1) * 256;
            for (int s = w; s < 20; s += 4) {
                const float* src = (s < 4) ? (Ut + (size_t)s * D + jn)
                                           : (W2 + (size_t)(s - 4) * D + jn);
                gload_lds16(src + lane * 4, &buf[cur ^ 1][s * 256 + lane * 4]);
            }
        }
        const float* bw = buf[cur];
        const int d0 = j * 256 + lane * 4;
        float4 ut[4];
        #pragma unroll
        for (int r = 0; r < 4; ++r)
            ut[r] = *reinterpret_cast<const float4*>(bw + r * 256 + lane * 4);
        float4 acc[2];
        #pragma unroll
        for (int tk = 0; tk < 2; ++tk) {
            const float4 xv = *reinterpret_cast<const float4*>(x + (size_t)(t0 + tk) * D + d0);  // L3-hot
            acc[tk].x = xv.x + hv[tk].x*ut[0].x + hv[tk].y*ut[1].x + hv[tk].z*ut[2].x + hv[tk].w*ut[3].x;
            acc[tk].y = xv.y + hv[tk].x*ut[0].y + hv[tk].y*ut[1].y + hv[tk].z*ut[2].y + hv[tk].w*ut[3].y;
            acc[tk].z = xv.z + hv[tk].x*ut[0].z + hv[tk].y*ut[1].z + hv[tk].z*ut[2].z + hv[tk].w*ut[3].z;
            acc[tk].w = xv.w + hv[tk].x*ut[0].w + hv[tk].y*ut[1].w + hv[tk].z*ut[2].w + hv[tk].w*ut[3].w;
        }
        #pragma unroll
        for (int f = 0; f < 16; ++f) {
            const float4 w2v = *reinterpret_cast<const float4*>(bw + 1024 + f * 256 + lane * 4);
            #pragma unroll
            for (int tk = 0; tk < 2; ++tk) {
                acc[tk].x += tvv[tk][f] * w2v.x;
                acc[tk].y += tvv[tk][f] * w2v.y;
                acc[tk].z += tvv[tk][f] * w2v.z;
                acc[tk].w += tvv[tk][f] * w2v.w;
            }
        }
        #pragma unroll
        for (int tk = 0; tk < 2; ++tk)
            *reinterpret_cast<float4*>(out + (size_t)(t0 + tk) * D + d0) = acc[tk];
        __syncthreads();
    }
}

extern "C" void kernel_launch(void* const* d_in, const int* in_sizes, int n_in,
                              void* d_out, int out_size, void* d_ws, size_t ws_size,
                              hipStream_t stream)
{
    (void)in_sizes; (void)n_in; (void)out_size; (void)ws_size;
    const float* x  = (const float*)d_in[0];
    const float* nw = (const float*)d_in[1];
    const float* V  = (const float*)d_in[2];
    const float* U  = (const float*)d_in[3];
    const float* al = (const float*)d_in[4];
    const float* W1 = (const float*)d_in[5];
    const float* W2 = (const float*)d_in[6];
    float* out = (float*)d_out;
    float* u   = (float*)d_ws;                 // [NTOK][4]
    float* hs  = u + (size_t)NTOK * 4;         // [NTOK][4]
    float* W1t = hs + (size_t)NTOK * 4;        // [16][D]
    float* Vt  = W1t + (size_t)16 * D;         // [4][D]
    float* Ut  = Vt + (size_t)4 * D;           // [4][D]
    // total workspace: 180224 floats = 704 KB

    k0_transpose  <<<dim3(192),       dim3(256),  0, stream>>>(W1, V, U, W1t, Vt, Ut);
    k1_u_kernel   <<<dim3(NTOK / 8),  dim3(256),  0, stream>>>(x, nw, Vt, u);
    k2_scan_kernel<<<dim3(NB),        dim3(1024), 0, stream>>>(u, al, hs);
    k3_fused_kernel<<<dim3(NTOK / 8), dim3(256),  0, stream>>>(x, nw, Ut, hs, W1t, W2, out);
}